// Round 3
// baseline (240.846 us; speedup 1.0000x reference)
//
#include <hip/hip_runtime.h>
#include <math.h>

#define NPTS 512
#define CH   128
#define NB   2
#define KVAL 460   // int(512 * (1 - 0.1))

typedef __attribute__((ext_vector_type(8))) short short8;
typedef __attribute__((ext_vector_type(4))) float f32x4;

union S8U { short8 s8; unsigned u[4]; };

__device__ __forceinline__ unsigned short f2bf_rne(float f) {
    unsigned int u = __float_as_uint(f);
    u += 0x7fffu + ((u >> 16) & 1u);
    return (unsigned short)(u >> 16);
}
// pack two f32 -> {bf16(a) lo, bf16(b) hi} by truncation: one v_perm_b32
__device__ __forceinline__ unsigned pk_trunc(float a, float b) {
    return __builtin_amdgcn_perm(__float_as_uint(b), __float_as_uint(a), 0x07060302u);
}
__device__ __forceinline__ float bf_lo(unsigned u) { return __uint_as_float(u << 16); }
__device__ __forceinline__ float bf_hi(unsigned u) { return __uint_as_float(u & 0xffff0000u); }

// Block = 32i x 16j tile, 4 waves: h = wave&1 (i-row within chunk), g = wave>>1
// (channel half). vj rows live in registers (bf16-packed, reused over all chunks).
// BN scales folded into bf16 weight fragments. LDS ~25.9 KB -> high residency.
__global__ __launch_bounds__(256, 3)
void mlp_mfma_kernel(const float* __restrict__ vp, const float* __restrict__ ep,
                     const float* __restrict__ W1,
                     const float* __restrict__ g1, const float* __restrict__ be1,
                     const float* __restrict__ m1, const float* __restrict__ v1,
                     const float* __restrict__ W2,
                     const float* __restrict__ g2, const float* __restrict__ be2,
                     const float* __restrict__ m2, const float* __restrict__ v2,
                     const float* __restrict__ W3, const float* __restrict__ b3,
                     float* __restrict__ ep_out, float* __restrict__ ns_out)
{
    __shared__ __align__(16) float    sVI[32*132];   // 16,896 B (stride132: 16B-aligned, bank shift 4)
    __shared__ __align__(16) unsigned sH1[32*68];    //  8,704 B u32 = 2 bf16 channels (stride 68 u32 = 272B)
    __shared__ float sPart[2][32];                   //    256 B

    const int t    = threadIdx.x;
    const int lane = t & 63;
    const int w    = t >> 6;
    const int h    = w & 1;
    const int g    = w >> 1;
    const int l15  = lane & 15;
    const int q    = lane >> 4;
    const int q8   = q * 8;
    const int b    = blockIdx.z;
    const int i0   = blockIdx.y * 32;
    const int j0   = blockIdx.x * 16;

    // ---- stage vp i-rows in fp32 (coalesced float4) ----
    for (int k = 0; k < 4; ++k) {
        int idx = k*256 + t;
        int r = idx >> 5, c4 = (idx & 31) * 4;
        *(float4*)&sVI[r*132 + c4] = *(const float4*)&vp[((size_t)(b*NPTS + i0 + r))*CH + c4];
    }

    // ---- vj row for this lane: 16 bf16-packed regs, fixed for whole block ----
    unsigned vjp[4][4];
    #pragma unroll
    for (int kt = 0; kt < 4; ++kt) {
        const float* p = &vp[((size_t)(b*NPTS + j0 + l15))*CH + kt*32 + q8];
        float4 x0 = *(const float4*)p;
        float4 x1 = *(const float4*)(p + 4);
        vjp[kt][0] = (unsigned)f2bf_rne(x0.x) | ((unsigned)f2bf_rne(x0.y) << 16);
        vjp[kt][1] = (unsigned)f2bf_rne(x0.z) | ((unsigned)f2bf_rne(x0.w) << 16);
        vjp[kt][2] = (unsigned)f2bf_rne(x1.x) | ((unsigned)f2bf_rne(x1.y) << 16);
        vjp[kt][3] = (unsigned)f2bf_rne(x1.z) | ((unsigned)f2bf_rne(x1.w) << 16);
    }

    // ---- W1 bf16 B-frags, BN1 scale folded; t1 shift kept separately ----
    short8 w1f[4][4];
    float  t1v[4];
    #pragma unroll
    for (int nt = 0; nt < 4; ++nt) {
        int o = g*64 + nt*16 + l15;
        float s = g1[o] * rsqrtf(v1[o] + 1e-5f);
        t1v[nt] = be1[o] - m1[o]*s;
        #pragma unroll
        for (int kt = 0; kt < 4; ++kt) {
            const float* p = &W1[(size_t)o*CH + kt*32 + q8];
            float4 x0 = *(const float4*)p;
            float4 x1 = *(const float4*)(p + 4);
            S8U u;
            u.u[0] = (unsigned)f2bf_rne(x0.x*s) | ((unsigned)f2bf_rne(x0.y*s) << 16);
            u.u[1] = (unsigned)f2bf_rne(x0.z*s) | ((unsigned)f2bf_rne(x0.w*s) << 16);
            u.u[2] = (unsigned)f2bf_rne(x1.x*s) | ((unsigned)f2bf_rne(x1.y*s) << 16);
            u.u[3] = (unsigned)f2bf_rne(x1.z*s) | ((unsigned)f2bf_rne(x1.w*s) << 16);
            w1f[nt][kt] = u.s8;
        }
    }
    // ---- W2 bf16 B-frags, BN2 folded ----
    short8 w2f[2][4];
    float  t2v[2], w3v[2];
    #pragma unroll
    for (int nt = 0; nt < 2; ++nt) {
        int o = g*32 + nt*16 + l15;
        float s = g2[o] * rsqrtf(v2[o] + 1e-5f);
        t2v[nt] = be2[o] - m2[o]*s;
        w3v[nt] = W3[o];
        #pragma unroll
        for (int kt = 0; kt < 4; ++kt) {
            const float* p = &W2[(size_t)o*CH + kt*32 + q8];
            float4 x0 = *(const float4*)p;
            float4 x1 = *(const float4*)(p + 4);
            S8U u;
            u.u[0] = (unsigned)f2bf_rne(x0.x*s) | ((unsigned)f2bf_rne(x0.y*s) << 16);
            u.u[1] = (unsigned)f2bf_rne(x0.z*s) | ((unsigned)f2bf_rne(x0.w*s) << 16);
            u.u[2] = (unsigned)f2bf_rne(x1.x*s) | ((unsigned)f2bf_rne(x1.y*s) << 16);
            u.u[3] = (unsigned)f2bf_rne(x1.z*s) | ((unsigned)f2bf_rne(x1.w*s) << 16);
            w2f[nt][kt] = u.s8;
        }
    }
    const float b3v = b3[0];
    __syncthreads();

    // ---- 16 chunks of 2 i-rows x 16 j = 32 pairs ----
    #pragma unroll 1
    for (int ch = 0; ch < 16; ++ch) {
        const int iirow = ch*2 + h;

        // ===== layer 1: A-frag (d^2) built in MFMA layout; ns free in ~fp32 =====
        short8 afr[4];
        float ns = 0.f;
        #pragma unroll
        for (int kt = 0; kt < 4; ++kt) {
            const float* vi = &sVI[iirow*132 + kt*32 + q8];   // broadcast (4 addrs/wave)
            float4 a0 = *(const float4*)vi, a1 = *(const float4*)(vi + 4);
            float c0 = bf_lo(vjp[kt][0]), c1 = bf_hi(vjp[kt][0]);
            float c2 = bf_lo(vjp[kt][1]), c3 = bf_hi(vjp[kt][1]);
            float c4 = bf_lo(vjp[kt][2]), c5 = bf_hi(vjp[kt][2]);
            float c6 = bf_lo(vjp[kt][3]), c7 = bf_hi(vjp[kt][3]);
            float d0 = a0.x - c0, d1 = a0.y - c1, d2 = a0.z - c2, d3 = a0.w - c3;
            float d4 = a1.x - c4, d5 = a1.y - c5, d6 = a1.z - c6, d7 = a1.w - c7;
            float p0 = d0*d0, p1 = d1*d1, p2 = d2*d2, p3 = d3*d3;
            float p4 = d4*d4, p5 = d5*d5, p6 = d6*d6, p7 = d7*d7;
            ns += ((p0 + p1) + (p2 + p3)) + ((p4 + p5) + (p6 + p7));
            S8U u;
            u.u[0] = pk_trunc(p0, p1);
            u.u[1] = pk_trunc(p2, p3);
            u.u[2] = pk_trunc(p4, p5);
            u.u[3] = pk_trunc(p6, p7);
            afr[kt] = u.s8;
        }
        ns += __shfl_xor(ns, 16);
        ns += __shfl_xor(ns, 32);
        if (g == 0 && lane < 16) {
            ns_out[((size_t)(b*NPTS + i0 + iirow))*NPTS + j0 + lane] = -ns;
        }

        #pragma unroll
        for (int nt = 0; nt < 4; ++nt) {
            f32x4 acc = {0.f, 0.f, 0.f, 0.f};
            acc = __builtin_amdgcn_mfma_f32_16x16x32_bf16(afr[0], w1f[nt][0], acc, 0, 0, 0);
            acc = __builtin_amdgcn_mfma_f32_16x16x32_bf16(afr[1], w1f[nt][1], acc, 0, 0, 0);
            acc = __builtin_amdgcn_mfma_f32_16x16x32_bf16(afr[2], w1f[nt][2], acc, 0, 0, 0);
            acc = __builtin_amdgcn_mfma_f32_16x16x32_bf16(afr[3], w1f[nt][3], acc, 0, 0, 0);
            // BN (scale folded) + lrelu; D: lane holds ch o=g*64+nt*16+l15, pairs jdx=q*4+r
            float hv0 = acc[0] + t1v[nt]; hv0 = hv0 > 0.f ? hv0 : hv0*0.01f;
            float hv1 = acc[1] + t1v[nt]; hv1 = hv1 > 0.f ? hv1 : hv1*0.01f;
            float hv2 = acc[2] + t1v[nt]; hv2 = hv2 > 0.f ? hv2 : hv2*0.01f;
            float hv3 = acc[3] + t1v[nt]; hv3 = hv3 > 0.f ? hv3 : hv3*0.01f;
            // pair channels (o even, o+1) via xor-1 exchange -> 2 x ds_write_b32
            float ov0 = __shfl_xor(hv0, 1);
            float ov1 = __shfl_xor(hv1, 1);
            float ov2 = __shfl_xor(hv2, 1);
            float ov3 = __shfl_xor(hv3, 1);
            bool odd = (l15 & 1);
            float lo0 = odd ? ov2 : hv0,  hi0 = odd ? hv2 : ov0;
            float lo1 = odd ? ov3 : hv1,  hi1 = odd ? hv3 : ov1;
            unsigned w0 = pk_trunc(lo0, hi0);
            unsigned w1 = pk_trunc(lo1, hi1);
            int col = g*32 + nt*8 + (l15 >> 1);
            int row = h*16 + q*4 + (odd ? 2 : 0);
            sH1[row*68 + col]     = w0;
            sH1[(row+1)*68 + col] = w1;
        }
        __syncthreads();

        // ===== layer 2 (+BN fold) + layer 3 dot =====
        short8 hfr[4];
        #pragma unroll
        for (int kt = 0; kt < 4; ++kt)
            hfr[kt] = *(const short8*)&sH1[(h*16 + l15)*68 + kt*16 + q*4];

        float part[4] = {0.f, 0.f, 0.f, 0.f};
        #pragma unroll
        for (int nt = 0; nt < 2; ++nt) {
            f32x4 acc = {0.f, 0.f, 0.f, 0.f};
            acc = __builtin_amdgcn_mfma_f32_16x16x32_bf16(hfr[0], w2f[nt][0], acc, 0, 0, 0);
            acc = __builtin_amdgcn_mfma_f32_16x16x32_bf16(hfr[1], w2f[nt][1], acc, 0, 0, 0);
            acc = __builtin_amdgcn_mfma_f32_16x16x32_bf16(hfr[2], w2f[nt][2], acc, 0, 0, 0);
            acc = __builtin_amdgcn_mfma_f32_16x16x32_bf16(hfr[3], w2f[nt][3], acc, 0, 0, 0);
            #pragma unroll
            for (int r = 0; r < 4; ++r) {
                float hv = acc[r] + t2v[nt];
                hv = hv > 0.f ? hv : hv*0.01f;
                part[r] = fmaf(hv, w3v[nt], part[r]);
            }
        }
        #pragma unroll
        for (int r = 0; r < 4; ++r) {
            part[r] += __shfl_xor(part[r], 1);
            part[r] += __shfl_xor(part[r], 2);
            part[r] += __shfl_xor(part[r], 4);
            part[r] += __shfl_xor(part[r], 8);
        }
        if (l15 == 0) {
            #pragma unroll
            for (int r = 0; r < 4; ++r)
                sPart[g][h*16 + q*4 + r] = part[r];
        }
        __syncthreads();

        // ===== epilogue: 32 pairs -> sigmoid * ep_last =====
        if (t < 32) {
            float logit = sPart[0][t] + sPart[1][t] + b3v;
            float sg = 1.f / (1.f + __expf(-logit));
            int i = i0 + ch*2 + (t >> 4);
            int j = j0 + (t & 15);
            float epl = (i == j) ? 0.f : ep[((size_t)(b*NPTS + i))*NPTS + j];
            ep_out[((size_t)(b*NPTS + i))*NPTS + j] = sg * epl;
        }
        // sH1 for chunk ch+1 is written only after this barrier-pair; safe.
    }
}

// ---- kernel 2: per-row top-k mask + L1 renorm + diag + row norm, in place ----
__device__ __forceinline__ float block_reduce_sum(float v, float* red) {
    #pragma unroll
    for (int off = 32; off; off >>= 1) v += __shfl_down(v, off);
    int wid = threadIdx.x >> 6;
    if ((threadIdx.x & 63) == 0) red[wid] = v;
    __syncthreads();
    float s = red[0] + red[1] + red[2] + red[3];
    __syncthreads();
    return s;
}

__global__ __launch_bounds__(256)
void topk_norm_kernel(const float* __restrict__ ep_gen, float* __restrict__ ep_io) {
    __shared__ __align__(16) float r[NPTS];
    __shared__ float red[4];
    const int row = blockIdx.x;          // b*512 + i
    const int i   = row & (NPTS - 1);
    const int t   = threadIdx.x;
    const float* gen = &ep_gen[(size_t)row * NPTS];
    float* io        = &ep_io [(size_t)row * NPTS];

    float v0 = io[t], v1 = io[t + 256];
    r[t] = v0; r[t + 256] = v1;
    float g0 = (t       == i) ? 0.f : gen[t];
    float g1 = (t + 256 == i) ? 0.f : gen[t + 256];
    __syncthreads();

    float s_last = block_reduce_sum(g0 + g1, red);

    // rank by strict-greater count. Values are sigmoid*uniform: exact float
    // ties are measure-zero (single diagonal zero per row), so the index
    // tiebreak of lax.top_k cannot change the kept set.
    int c0 = 0, c1 = 0;
    #pragma unroll 4
    for (int k = 0; k < NPTS; k += 4) {
        float4 rv = *(const float4*)&r[k];
        c0 += (rv.x > v0) + (rv.y > v0) + (rv.z > v0) + (rv.w > v0);
        c1 += (rv.x > v1) + (rv.y > v1) + (rv.z > v1) + (rv.w > v1);
    }
    float m0 = (c0 < KVAL) ? v0 : 0.f;
    float m1 = (c1 < KVAL) ? v1 : 0.f;

    float l1 = block_reduce_sum(m0 + m1, red);
    l1 = fmaxf(l1, 1e-12f);
    float scale = s_last / l1;
    float f0 = m0*scale + ((t       == i) ? 1.f : 0.f) + 1e-6f;
    float f1 = m1*scale + ((t + 256 == i) ? 1.f : 0.f) + 1e-6f;

    float s2 = block_reduce_sum(f0 + f1, red);
    float inv = 1.f / s2;
    io[t]       = f0 * inv;
    io[t + 256] = f1 * inv;
}

extern "C" void kernel_launch(void* const* d_in, const int* in_sizes, int n_in,
                              void* d_out, int out_size, void* d_ws, size_t ws_size,
                              hipStream_t stream) {
    const float* vp  = (const float*)d_in[0];
    const float* ep  = (const float*)d_in[1];
    const float* W1  = (const float*)d_in[2];
    const float* g1  = (const float*)d_in[3];
    const float* be1 = (const float*)d_in[4];
    const float* m1  = (const float*)d_in[5];
    const float* v1  = (const float*)d_in[6];
    const float* W2  = (const float*)d_in[7];
    const float* g2  = (const float*)d_in[8];
    const float* be2 = (const float*)d_in[9];
    const float* m2  = (const float*)d_in[10];
    const float* v2  = (const float*)d_in[11];
    const float* W3  = (const float*)d_in[12];
    const float* b3  = (const float*)d_in[13];

    float* out    = (float*)d_out;
    float* ep_out = out;                          // [2,512,512]
    float* ns_out = out + (size_t)NB*NPTS*NPTS;   // [2,512,512]

    dim3 grid(NPTS/16, NPTS/32, NB);              // 1024 blocks
    mlp_mfma_kernel<<<grid, dim3(256), 0, stream>>>(vp, ep, W1, g1, be1, m1, v1,
                                                    W2, g2, be2, m2, v2, W3, b3,
                                                    ep_out, ns_out);
    topk_norm_kernel<<<dim3(NB*NPTS), dim3(256), 0, stream>>>(ep, ep_out);
}